// Round 1
// baseline (741.845 us; speedup 1.0000x reference)
//
#include <hip/hip_runtime.h>
#include <stdint.h>

#define D 256
#define TPB 256

typedef __attribute__((ext_vector_type(8))) short short8;
typedef __attribute__((ext_vector_type(4))) short short4v;
typedef __attribute__((ext_vector_type(4))) float f32x4;

__device__ inline unsigned short f2bf(float f) {
    union { float f; uint32_t u; } c; c.f = f;
    uint32_t u = c.u;
    // round-to-nearest-even bf16
    uint32_t r = (u + 0x7FFFu + ((u >> 16) & 1u)) >> 16;
    return (unsigned short)r;
}

__global__ void k_zero(int* __restrict__ p, int n) {
    int i = blockIdx.x * blockDim.x + threadIdx.x;
    if (i < n) p[i] = 0;
}

__global__ void k_deg(const int* __restrict__ dst, int* __restrict__ deg, int ne) {
    int i = blockIdx.x * blockDim.x + threadIdx.x;
    if (i < ne) atomicAdd(&deg[dst[i]], 1);
}

// single-block two-phase exclusive scan: offs[0..n], offs[n] = total
__global__ void k_scan(const int* __restrict__ deg, int* __restrict__ offs, int n) {
    __shared__ int sums[TPB];
    int t = threadIdx.x;
    int chunk = (n + TPB - 1) / TPB;
    int start = t * chunk;
    int end = min(start + chunk, n);
    int s = 0;
    for (int i = start; i < end; ++i) s += deg[i];
    sums[t] = s;
    __syncthreads();
    if (t == 0) {
        int r = 0;
        for (int j = 0; j < TPB; ++j) { int v = sums[j]; sums[j] = r; r += v; }
        offs[n] = r;
    }
    __syncthreads();
    int r = sums[t];
    for (int i = start; i < end; ++i) { offs[i] = r; r += deg[i]; }
}

__global__ void k_dinv(const int* __restrict__ deg, float* __restrict__ dinv, int n) {
    int i = blockIdx.x * blockDim.x + threadIdx.x;
    // reference: deg includes self-loop -> indeg + 1 (always > 0)
    if (i < n) dinv[i] = rsqrtf((float)(deg[i] + 1));
}

__global__ void k_fill(const int* __restrict__ src, const int* __restrict__ dst,
                       const int* __restrict__ offs, int* __restrict__ cur,
                       int* __restrict__ csr, int ne) {
    int i = blockIdx.x * blockDim.x + threadIdx.x;
    if (i < ne) {
        int d = dst[i];
        int p = atomicAdd(&cur[d], 1);
        csr[offs[d] + p] = src[i];
    }
}

// Wt[n][k] = W[k][n] as bf16  (W is KxN = 256x256)
__global__ void k_wt(const float* __restrict__ W, unsigned short* __restrict__ Wt) {
    int idx = blockIdx.x * 256 + threadIdx.x;  // 65536 total
    int n = idx >> 8, k = idx & 255;
    Wt[n * 256 + k] = f2bf(W[k * 256 + n]);
}

// C[M,256] = A[M,256] @ B[256,256], B given transposed-bf16 as Bt[n][k].
// Block: 256 thr = 4 waves; BM=64 (16 rows per wave), BN=256, full K in LDS.
__global__ __launch_bounds__(256) void k_gemm(const float* __restrict__ A,
                                              const unsigned short* __restrict__ Bt,
                                              float* __restrict__ C, int M) {
    __shared__ unsigned short sA[64][264];  // +8 pad: breaks bank aliasing
    int bm = blockIdx.x * 64;
    int t = threadIdx.x;
    // stage A tile (64x256 fp32 -> bf16 LDS), coalesced float4 loads
    for (int i = 0; i < 16; ++i) {
        int idx = i * 256 + t;      // float4 id in tile
        int row = idx >> 6;         // 64 float4 per row
        int c4 = idx & 63;
        int gr = bm + row;
        f32x4 v = {0.f, 0.f, 0.f, 0.f};
        if (gr < M) v = *reinterpret_cast<const f32x4*>(A + (size_t)gr * D + c4 * 4);
        short4v sv;
        sv.x = (short)f2bf(v.x);
        sv.y = (short)f2bf(v.y);
        sv.z = (short)f2bf(v.z);
        sv.w = (short)f2bf(v.w);
        *reinterpret_cast<short4v*>(&sA[row][c4 * 4]) = sv;
    }
    __syncthreads();

    int wave = t >> 6, lane = t & 63;
    int quad = lane >> 4, l16 = lane & 15;
    int mloc = wave * 16 + l16;

    f32x4 acc[16];
#pragma unroll
    for (int nt = 0; nt < 16; ++nt) acc[nt] = (f32x4){0.f, 0.f, 0.f, 0.f};

#pragma unroll
    for (int k0 = 0; k0 < 256; k0 += 32) {
        short8 a = *reinterpret_cast<const short8*>(&sA[mloc][k0 + quad * 8]);
#pragma unroll
        for (int nt = 0; nt < 16; ++nt) {
            short8 b = *reinterpret_cast<const short8*>(Bt + (nt * 16 + l16) * D + k0 + quad * 8);
            acc[nt] = __builtin_amdgcn_mfma_f32_16x16x32_bf16(a, b, acc[nt], 0, 0, 0);
        }
    }

    int rb = bm + wave * 16 + quad * 4;
#pragma unroll
    for (int nt = 0; nt < 16; ++nt) {
        int col = nt * 16 + l16;
#pragma unroll
        for (int r = 0; r < 4; ++r) {
            int row = rb + r;
            if (row < M) C[(size_t)row * D + col] = acc[nt][r];
        }
    }
}

// one wave per node: gather-aggregate (CSR) + bias + LayerNorm + ReLU
__global__ __launch_bounds__(256) void k_agg(const float* __restrict__ h,
                                             const int* __restrict__ offs,
                                             const int* __restrict__ csr,
                                             const float* __restrict__ dinv,
                                             const float* __restrict__ bias,
                                             const float* __restrict__ lnw,
                                             const float* __restrict__ lnb,
                                             float* __restrict__ out, int n) {
    int wave = threadIdx.x >> 6, lane = threadIdx.x & 63;
    int node = blockIdx.x * 4 + wave;
    if (node >= n) return;
    const f32x4* h4 = (const f32x4*)h;
    float di = dinv[node];
    f32x4 acc = h4[(size_t)node * 64 + lane] * (di * di);  // self-loop term
    int e0 = offs[node], e1 = offs[node + 1];
    for (int e = e0; e < e1; ++e) {
        int s = csr[e];
        float w = dinv[s] * di;
        acc += h4[(size_t)s * 64 + lane] * w;
    }
    acc += ((const f32x4*)bias)[lane];

    float s1 = acc.x + acc.y + acc.z + acc.w;
    float s2 = acc.x * acc.x + acc.y * acc.y + acc.z * acc.z + acc.w * acc.w;
#pragma unroll
    for (int o = 32; o > 0; o >>= 1) {
        s1 += __shfl_xor(s1, o, 64);
        s2 += __shfl_xor(s2, o, 64);
    }
    float mean = s1 * (1.0f / 256.0f);
    float var = s2 * (1.0f / 256.0f) - mean * mean;
    float inv = rsqrtf(var + 1e-5f);
    f32x4 w4 = ((const f32x4*)lnw)[lane];
    f32x4 lb = ((const f32x4*)lnb)[lane];
    f32x4 y;
    y.x = fmaxf((acc.x - mean) * inv * w4.x + lb.x, 0.f);
    y.y = fmaxf((acc.y - mean) * inv * w4.y + lb.y, 0.f);
    y.z = fmaxf((acc.z - mean) * inv * w4.z + lb.z, 0.f);
    y.w = fmaxf((acc.w - mean) * inv * w4.w + lb.w, 0.f);
    ((f32x4*)out)[(size_t)node * 64 + lane] = y;
}

// one block per graph: mean-pool (batch sorted -> binary search) + linear
__global__ __launch_bounds__(256) void k_pool(const float* __restrict__ h,
                                              const int* __restrict__ batch,
                                              const float* __restrict__ linW,
                                              const float* __restrict__ linb,
                                              float* __restrict__ out,
                                              int nNodes) {
    int g = blockIdx.x, t = threadIdx.x;
    int lo = 0, hi = nNodes;
    while (lo < hi) { int m = (lo + hi) >> 1; if (batch[m] < g) lo = m + 1; else hi = m; }
    int lo2 = lo, hi2 = nNodes;
    while (lo2 < hi2) { int m = (lo2 + hi2) >> 1; if (batch[m] < g + 1) lo2 = m + 1; else hi2 = m; }
    float s = 0.f;
    for (int i = lo; i < lo2; ++i) s += h[(size_t)i * D + t];
    float cnt = (float)(lo2 - lo);
    float pooled = s / fmaxf(cnt, 1.f);
    __shared__ float sp[256];
    __shared__ float red[4];
    sp[t] = pooled;
    __syncthreads();
    for (int c = 0; c < 10; ++c) {
        float v = sp[t] * linW[t * 10 + c];
#pragma unroll
        for (int o = 32; o > 0; o >>= 1) v += __shfl_xor(v, o, 64);
        if ((t & 63) == 0) red[t >> 6] = v;
        __syncthreads();
        if (t == 0) out[g * 10 + c] = red[0] + red[1] + red[2] + red[3] + linb[c];
        __syncthreads();
    }
}

extern "C" void kernel_launch(void* const* d_in, const int* in_sizes, int n_in,
                              void* d_out, int out_size, void* d_ws, size_t ws_size,
                              hipStream_t stream) {
    const float* x    = (const float*)d_in[0];
    const int*   ei   = (const int*)d_in[1];
    const int*   batch= (const int*)d_in[2];
    const float* W1   = (const float*)d_in[3];
    const float* b1   = (const float*)d_in[4];
    const float* W2   = (const float*)d_in[5];
    const float* b2   = (const float*)d_in[6];
    const float* ln1w = (const float*)d_in[7];
    const float* ln1b = (const float*)d_in[8];
    const float* ln2w = (const float*)d_in[9];
    const float* ln2b = (const float*)d_in[10];
    const float* linW = (const float*)d_in[11];
    const float* linb = (const float*)d_in[12];
    float* out = (float*)d_out;

    int nNodes  = in_sizes[0] / D;   // 50000
    int nEdges  = in_sizes[1] / 2;   // 800000
    int nGraphs = out_size / 10;     // 512

    const int* src = ei;
    const int* dst = ei + nEdges;

    char* ws = (char*)d_ws;
    size_t o = 0;
    auto alloc = [&](size_t bytes) -> char* {
        char* p = ws + o;
        o += (bytes + 511) & ~(size_t)511;
        return p;
    };
    float* hW  = (float*)alloc((size_t)nNodes * D * 4);
    float* h1  = (float*)alloc((size_t)nNodes * D * 4);
    int* deg   = (int*)alloc((size_t)nNodes * 4);
    int* cur   = (int*)alloc((size_t)nNodes * 4);
    int* offs  = (int*)alloc((size_t)(nNodes + 1) * 4);
    int* csr   = (int*)alloc((size_t)nEdges * 4);
    float* dinv= (float*)alloc((size_t)nNodes * 4);
    unsigned short* Wt = (unsigned short*)alloc((size_t)D * D * 2);
    (void)ws_size;

    int gn = (nNodes + 255) / 256;
    int ge = (nEdges + 255) / 256;

    // CSR build (dst-sorted counting sort, int atomics only)
    k_zero<<<gn, 256, 0, stream>>>(deg, nNodes);
    k_zero<<<gn, 256, 0, stream>>>(cur, nNodes);
    k_deg <<<ge, 256, 0, stream>>>(dst, deg, nEdges);
    k_scan<<<1, TPB, 0, stream>>>(deg, offs, nNodes);
    k_dinv<<<gn, 256, 0, stream>>>(deg, dinv, nNodes);
    k_fill<<<ge, 256, 0, stream>>>(src, dst, offs, cur, csr, nEdges);

    // layer 1
    k_wt  <<<D, 256, 0, stream>>>(W1, Wt);
    k_gemm<<<(nNodes + 63) / 64, 256, 0, stream>>>(x, Wt, hW, nNodes);
    k_agg <<<(nNodes + 3) / 4, 256, 0, stream>>>(hW, offs, csr, dinv, b1, ln1w, ln1b, h1, nNodes);

    // layer 2 (reuse hW; h1 -> overwritten after gemm consumed it)
    k_wt  <<<D, 256, 0, stream>>>(W2, Wt);
    k_gemm<<<(nNodes + 63) / 64, 256, 0, stream>>>(h1, Wt, hW, nNodes);
    k_agg <<<(nNodes + 3) / 4, 256, 0, stream>>>(hW, offs, csr, dinv, b2, ln2w, ln2b, h1, nNodes);

    // pool + classifier
    k_pool<<<nGraphs, 256, 0, stream>>>(h1, batch, linW, linb, out, nNodes);
}

// Round 2
// 668.689 us; speedup vs baseline: 1.1094x; 1.1094x over previous
//
#include <hip/hip_runtime.h>
#include <stdint.h>

#define D 256
#define TPB 256

typedef __attribute__((ext_vector_type(8))) short short8;
typedef __attribute__((ext_vector_type(4))) float f32x4;

__device__ inline unsigned short f2bf(float f) {
    uint32_t u = __builtin_bit_cast(uint32_t, f);
    uint32_t r = (u + 0x7FFFu + ((u >> 16) & 1u)) >> 16;  // RNE
    return (unsigned short)r;
}

__device__ inline f32x4 bf4_to_f32(uint2 v) {
    f32x4 r;
    r.x = __builtin_bit_cast(float, v.x << 16);
    r.y = __builtin_bit_cast(float, v.x & 0xFFFF0000u);
    r.z = __builtin_bit_cast(float, v.y << 16);
    r.w = __builtin_bit_cast(float, v.y & 0xFFFF0000u);
    return r;
}

__global__ void k_zero2(int* __restrict__ a, int* __restrict__ b, int n) {
    int i = blockIdx.x * blockDim.x + threadIdx.x;
    if (i < n) { a[i] = 0; b[i] = 0; }
}

__global__ void k_deg(const int* __restrict__ dst, int* __restrict__ deg, int ne) {
    int i = blockIdx.x * blockDim.x + threadIdx.x;
    if (i < ne) atomicAdd(&deg[dst[i]], 1);
}

// single-block: exclusive scan of deg -> offs[0..n] (offs[n]=total), plus dinv
__global__ void k_scan(const int* __restrict__ deg, int* __restrict__ offs,
                       float* __restrict__ dinv, int n) {
    __shared__ int sums[TPB];
    int t = threadIdx.x;
    int chunk = (n + TPB - 1) / TPB;
    int start = t * chunk;
    int end = min(start + chunk, n);
    int s = 0;
    for (int i = start; i < end; ++i) {
        int d = deg[i];
        s += d;
        dinv[i] = rsqrtf((float)(d + 1));  // +1 self-loop, always > 0
    }
    sums[t] = s;
    __syncthreads();
    if (t == 0) {
        int r = 0;
        for (int j = 0; j < TPB; ++j) { int v = sums[j]; sums[j] = r; r += v; }
        offs[n] = r;
    }
    __syncthreads();
    int r = sums[t];
    for (int i = start; i < end; ++i) { offs[i] = r; r += deg[i]; }
}

// CSR fill with fused per-edge weight: ew[e] = (src, bits(dinv[src]))
__global__ void k_fill(const int* __restrict__ src, const int* __restrict__ dst,
                       const int* __restrict__ offs, int* __restrict__ cur,
                       const float* __restrict__ dinv, int2* __restrict__ ew, int ne) {
    int i = blockIdx.x * blockDim.x + threadIdx.x;
    if (i < ne) {
        int s = src[i], d = dst[i];
        int p = atomicAdd(&cur[d], 1);
        int2 e;
        e.x = s;
        e.y = __builtin_bit_cast(int, dinv[s]);
        ew[offs[d] + p] = e;
    }
}

// Wt[n][k] = bf16(W[k][n])  (W is 256x256 row-major KxN)
__global__ void k_wt(const float* __restrict__ W, unsigned short* __restrict__ Wt) {
    int idx = blockIdx.x * 256 + threadIdx.x;
    int n = idx >> 8, k = idx & 255;
    Wt[n * 256 + k] = f2bf(W[k * 256 + n]);
}

// C[M,256](bf16) = A[M,256](fp32) @ B, B as bf16 Bt[n][k]. No LDS:
// A fragments loaded directly in MFMA layout, converted once per element.
// Block 256 thr = 4 waves, BM=128 (2 m-subtiles of 16 per wave).
__global__ __launch_bounds__(256, 1) void k_gemm(const float* __restrict__ A,
                                                 const unsigned short* __restrict__ Bt,
                                                 unsigned short* __restrict__ Cb, int M) {
    int t = threadIdx.x;
    int wave = t >> 6, lane = t & 63;
    int quad = lane >> 4, l16 = lane & 15;
    int bm = blockIdx.x * 128;

    // A fragments: af[sub][k0], lane covers A[m=l16][k = k0*32 + quad*8 + j]
    short8 af[2][8];
#pragma unroll
    for (int s = 0; s < 2; ++s) {
        int row = bm + wave * 32 + s * 16 + l16;
        if (row >= M) row = M - 1;  // clamp: loads stay in-bounds, stores masked
        const float* ap = A + (size_t)row * D + quad * 8;
#pragma unroll
        for (int k0 = 0; k0 < 8; ++k0) {
            f32x4 v0 = *reinterpret_cast<const f32x4*>(ap + k0 * 32);
            f32x4 v1 = *reinterpret_cast<const f32x4*>(ap + k0 * 32 + 4);
            short8 a;
            a[0] = (short)f2bf(v0.x); a[1] = (short)f2bf(v0.y);
            a[2] = (short)f2bf(v0.z); a[3] = (short)f2bf(v0.w);
            a[4] = (short)f2bf(v1.x); a[5] = (short)f2bf(v1.y);
            a[6] = (short)f2bf(v1.z); a[7] = (short)f2bf(v1.w);
            af[s][k0] = a;
        }
    }

    f32x4 acc[2][16];
#pragma unroll
    for (int s = 0; s < 2; ++s)
#pragma unroll
        for (int nt = 0; nt < 16; ++nt) acc[s][nt] = (f32x4){0.f, 0.f, 0.f, 0.f};

#pragma unroll 2
    for (int nt = 0; nt < 16; ++nt) {
        const unsigned short* bp = Bt + (size_t)(nt * 16 + l16) * D + quad * 8;
        short8 bf[8];
#pragma unroll
        for (int k0 = 0; k0 < 8; ++k0)
            bf[k0] = *reinterpret_cast<const short8*>(bp + k0 * 32);
#pragma unroll
        for (int k0 = 0; k0 < 8; ++k0) {
            acc[0][nt] = __builtin_amdgcn_mfma_f32_16x16x32_bf16(af[0][k0], bf[k0], acc[0][nt], 0, 0, 0);
            acc[1][nt] = __builtin_amdgcn_mfma_f32_16x16x32_bf16(af[1][k0], bf[k0], acc[1][nt], 0, 0, 0);
        }
    }

#pragma unroll
    for (int s = 0; s < 2; ++s) {
        int rb = bm + wave * 32 + s * 16 + quad * 4;
#pragma unroll
        for (int nt = 0; nt < 16; ++nt) {
            int col = nt * 16 + l16;
#pragma unroll
            for (int r = 0; r < 4; ++r) {
                int row = rb + r;
                if (row < M) Cb[(size_t)row * D + col] = f2bf(acc[s][nt][r]);
            }
        }
    }
}

// one wave per node: bf16 gather-aggregate + bias + LayerNorm + ReLU -> fp32
__global__ __launch_bounds__(256) void k_agg(const unsigned short* __restrict__ hb,
                                             const int* __restrict__ offs,
                                             const int2* __restrict__ ew,
                                             const float* __restrict__ dinv,
                                             const float* __restrict__ bias,
                                             const float* __restrict__ lnw,
                                             const float* __restrict__ lnb,
                                             float* __restrict__ out, int n) {
    int wave = threadIdx.x >> 6, lane = threadIdx.x & 63;
    int node = blockIdx.x * 4 + wave;
    if (node >= n) return;
    float di = dinv[node];
    uint2 rs = *reinterpret_cast<const uint2*>(hb + (size_t)node * D + lane * 4);
    f32x4 acc = bf4_to_f32(rs) * (di * di);  // self-loop term
    int e0 = offs[node], e1 = offs[node + 1];
    int e = e0;
#pragma unroll 1
    for (; e + 4 <= e1; e += 4) {
        int2 p0 = ew[e + 0], p1 = ew[e + 1], p2 = ew[e + 2], p3 = ew[e + 3];
        uint2 r0 = *reinterpret_cast<const uint2*>(hb + (size_t)p0.x * D + lane * 4);
        uint2 r1 = *reinterpret_cast<const uint2*>(hb + (size_t)p1.x * D + lane * 4);
        uint2 r2 = *reinterpret_cast<const uint2*>(hb + (size_t)p2.x * D + lane * 4);
        uint2 r3 = *reinterpret_cast<const uint2*>(hb + (size_t)p3.x * D + lane * 4);
        acc += bf4_to_f32(r0) * (__builtin_bit_cast(float, p0.y) * di);
        acc += bf4_to_f32(r1) * (__builtin_bit_cast(float, p1.y) * di);
        acc += bf4_to_f32(r2) * (__builtin_bit_cast(float, p2.y) * di);
        acc += bf4_to_f32(r3) * (__builtin_bit_cast(float, p3.y) * di);
    }
    for (; e < e1; ++e) {
        int2 p = ew[e];
        uint2 r = *reinterpret_cast<const uint2*>(hb + (size_t)p.x * D + lane * 4);
        acc += bf4_to_f32(r) * (__builtin_bit_cast(float, p.y) * di);
    }
    acc += ((const f32x4*)bias)[lane];

    float s1 = acc.x + acc.y + acc.z + acc.w;
    float s2 = acc.x * acc.x + acc.y * acc.y + acc.z * acc.z + acc.w * acc.w;
#pragma unroll
    for (int o = 32; o > 0; o >>= 1) {
        s1 += __shfl_xor(s1, o, 64);
        s2 += __shfl_xor(s2, o, 64);
    }
    float mean = s1 * (1.0f / 256.0f);
    float var = s2 * (1.0f / 256.0f) - mean * mean;
    float inv = rsqrtf(var + 1e-5f);
    f32x4 w4 = ((const f32x4*)lnw)[lane];
    f32x4 lb = ((const f32x4*)lnb)[lane];
    f32x4 y;
    y.x = fmaxf((acc.x - mean) * inv * w4.x + lb.x, 0.f);
    y.y = fmaxf((acc.y - mean) * inv * w4.y + lb.y, 0.f);
    y.z = fmaxf((acc.z - mean) * inv * w4.z + lb.z, 0.f);
    y.w = fmaxf((acc.w - mean) * inv * w4.w + lb.w, 0.f);
    ((f32x4*)out)[(size_t)node * 64 + lane] = y;
}

// one block per graph: mean-pool (batch sorted -> binary search) + linear
__global__ __launch_bounds__(256) void k_pool(const float* __restrict__ h,
                                              const int* __restrict__ batch,
                                              const float* __restrict__ linW,
                                              const float* __restrict__ linb,
                                              float* __restrict__ out,
                                              int nNodes) {
    int g = blockIdx.x, t = threadIdx.x;
    int lo = 0, hi = nNodes;
    while (lo < hi) { int m = (lo + hi) >> 1; if (batch[m] < g) lo = m + 1; else hi = m; }
    int lo2 = lo, hi2 = nNodes;
    while (lo2 < hi2) { int m = (lo2 + hi2) >> 1; if (batch[m] < g + 1) lo2 = m + 1; else hi2 = m; }
    float s = 0.f;
    for (int i = lo; i < lo2; ++i) s += h[(size_t)i * D + t];
    float cnt = (float)(lo2 - lo);
    float pooled = s / fmaxf(cnt, 1.f);
    __shared__ float sp[256];
    __shared__ float red[4];
    sp[t] = pooled;
    __syncthreads();
    for (int c = 0; c < 10; ++c) {
        float v = sp[t] * linW[t * 10 + c];
#pragma unroll
        for (int o = 32; o > 0; o >>= 1) v += __shfl_xor(v, o, 64);
        if ((t & 63) == 0) red[t >> 6] = v;
        __syncthreads();
        if (t == 0) out[g * 10 + c] = red[0] + red[1] + red[2] + red[3] + linb[c];
        __syncthreads();
    }
}

extern "C" void kernel_launch(void* const* d_in, const int* in_sizes, int n_in,
                              void* d_out, int out_size, void* d_ws, size_t ws_size,
                              hipStream_t stream) {
    const float* x    = (const float*)d_in[0];
    const int*   ei   = (const int*)d_in[1];
    const int*   batch= (const int*)d_in[2];
    const float* W1   = (const float*)d_in[3];
    const float* b1   = (const float*)d_in[4];
    const float* W2   = (const float*)d_in[5];
    const float* b2   = (const float*)d_in[6];
    const float* ln1w = (const float*)d_in[7];
    const float* ln1b = (const float*)d_in[8];
    const float* ln2w = (const float*)d_in[9];
    const float* ln2b = (const float*)d_in[10];
    const float* linW = (const float*)d_in[11];
    const float* linb = (const float*)d_in[12];
    float* out = (float*)d_out;

    int nNodes  = in_sizes[0] / D;   // 50000
    int nEdges  = in_sizes[1] / 2;   // 800000
    int nGraphs = out_size / 10;     // 512

    const int* src = ei;
    const int* dst = ei + nEdges;

    char* ws = (char*)d_ws;
    size_t o = 0;
    auto alloc = [&](size_t bytes) -> char* {
        char* p = ws + o;
        o += (bytes + 511) & ~(size_t)511;
        return p;
    };
    unsigned short* hW = (unsigned short*)alloc((size_t)nNodes * D * 2);  // bf16 gather target
    float* h1  = (float*)alloc((size_t)nNodes * D * 4);                   // fp32 LN output
    int* deg   = (int*)alloc((size_t)nNodes * 4);
    int* cur   = (int*)alloc((size_t)nNodes * 4);
    int* offs  = (int*)alloc((size_t)(nNodes + 1) * 4);
    int2* ew   = (int2*)alloc((size_t)nEdges * 8);
    float* dinv= (float*)alloc((size_t)nNodes * 4);
    unsigned short* Wt = (unsigned short*)alloc((size_t)D * D * 2);
    (void)ws_size;

    int gn = (nNodes + 255) / 256;
    int ge = (nEdges + 255) / 256;

    // CSR build (dst counting sort; per-edge weight fused)
    k_zero2<<<gn, 256, 0, stream>>>(deg, cur, nNodes);
    k_deg <<<ge, 256, 0, stream>>>(dst, deg, nEdges);
    k_scan<<<1, TPB, 0, stream>>>(deg, offs, dinv, nNodes);
    k_fill<<<ge, 256, 0, stream>>>(src, dst, offs, cur, dinv, ew, nEdges);

    // layer 1
    k_wt  <<<D, 256, 0, stream>>>(W1, Wt);
    k_gemm<<<(nNodes + 127) / 128, 256, 0, stream>>>(x, Wt, hW, nNodes);
    k_agg <<<(nNodes + 3) / 4, 256, 0, stream>>>(hW, offs, ew, dinv, b1, ln1w, ln1b, h1, nNodes);

    // layer 2
    k_wt  <<<D, 256, 0, stream>>>(W2, Wt);
    k_gemm<<<(nNodes + 127) / 128, 256, 0, stream>>>(h1, Wt, hW, nNodes);
    k_agg <<<(nNodes + 3) / 4, 256, 0, stream>>>(hW, offs, ew, dinv, b2, ln2w, ln2b, h1, nNodes);

    // pool + classifier
    k_pool<<<nGraphs, 256, 0, stream>>>(h1, batch, linW, linb, out, nNodes);
}

// Round 3
// 546.093 us; speedup vs baseline: 1.3585x; 1.2245x over previous
//
#include <hip/hip_runtime.h>
#include <stdint.h>

#define D 256
#define TPB 256

typedef __attribute__((ext_vector_type(8))) short short8;
typedef __attribute__((ext_vector_type(4))) float f32x4;

__device__ inline unsigned short f2bf(float f) {
    uint32_t u = __builtin_bit_cast(uint32_t, f);
    uint32_t r = (u + 0x7FFFu + ((u >> 16) & 1u)) >> 16;  // RNE
    return (unsigned short)r;
}

__device__ inline f32x4 bf4_to_f32(uint2 v) {
    f32x4 r;
    r.x = __builtin_bit_cast(float, v.x << 16);
    r.y = __builtin_bit_cast(float, v.x & 0xFFFF0000u);
    r.z = __builtin_bit_cast(float, v.y << 16);
    r.w = __builtin_bit_cast(float, v.y & 0xFFFF0000u);
    return r;
}

__global__ void k_zero2(int* __restrict__ a, int* __restrict__ b, int n) {
    int i = blockIdx.x * blockDim.x + threadIdx.x;
    if (i < n) { a[i] = 0; b[i] = 0; }
}

__global__ void k_deg(const int* __restrict__ dst, int* __restrict__ deg, int ne) {
    int i = blockIdx.x * blockDim.x + threadIdx.x;
    if (i < ne) atomicAdd(&deg[dst[i]], 1);
}

// phase 1: per-block sum of deg (256 elems/block, coalesced) + dinv
__global__ __launch_bounds__(256) void k_scan1(const int* __restrict__ deg,
                                               float* __restrict__ dinv,
                                               int* __restrict__ bsum, int n) {
    int t = threadIdx.x, i = blockIdx.x * 256 + t;
    int d = 0;
    if (i < n) {
        d = deg[i];
        dinv[i] = rsqrtf((float)(d + 1));  // +1 self-loop, always > 0
    }
    int s = d;
#pragma unroll
    for (int o = 32; o > 0; o >>= 1) s += __shfl_xor(s, o, 64);
    __shared__ int red[4];
    if ((t & 63) == 0) red[t >> 6] = s;
    __syncthreads();
    if (t == 0) bsum[blockIdx.x] = red[0] + red[1] + red[2] + red[3];
}

// phase 2: single block, exclusive scan of bsum[nb] (nb<=256); offs[n]=total
__global__ __launch_bounds__(256) void k_scan2(int* __restrict__ bsum,
                                               int* __restrict__ offs, int nb, int n) {
    __shared__ int sh[256];
    int t = threadIdx.x;
    int v = (t < nb) ? bsum[t] : 0;
    sh[t] = v;
    __syncthreads();
#pragma unroll
    for (int o = 1; o < 256; o <<= 1) {
        int u = (t >= o) ? sh[t - o] : 0;
        __syncthreads();
        sh[t] += u;
        __syncthreads();
    }
    if (t < nb) bsum[t] = sh[t] - v;    // exclusive base per block
    if (t == 0) offs[n] = sh[255];      // total
}

// phase 3: per-block exclusive scan of its 256 deg elems + base -> offs
__global__ __launch_bounds__(256) void k_scan3(const int* __restrict__ deg,
                                               const int* __restrict__ bsum,
                                               int* __restrict__ offs, int n) {
    int t = threadIdx.x, i = blockIdx.x * 256 + t;
    int d = (i < n) ? deg[i] : 0;
    __shared__ int sh[256];
    sh[t] = d;
    __syncthreads();
#pragma unroll
    for (int o = 1; o < 256; o <<= 1) {
        int u = (t >= o) ? sh[t - o] : 0;
        __syncthreads();
        sh[t] += u;
        __syncthreads();
    }
    if (i < n) offs[i] = bsum[blockIdx.x] + sh[t] - d;
}

// CSR fill with fused per-edge weight: ew[e] = (src, bits(dinv[src]))
__global__ void k_fill(const int* __restrict__ src, const int* __restrict__ dst,
                       const int* __restrict__ offs, int* __restrict__ cur,
                       const float* __restrict__ dinv, int2* __restrict__ ew, int ne) {
    int i = blockIdx.x * blockDim.x + threadIdx.x;
    if (i < ne) {
        int s = src[i], d = dst[i];
        int p = atomicAdd(&cur[d], 1);
        int2 e;
        e.x = s;
        e.y = __builtin_bit_cast(int, dinv[s]);
        ew[offs[d] + p] = e;
    }
}

// Wt[n][k] = bf16(W[k][n])  (W is 256x256 row-major KxN)
__global__ void k_wt(const float* __restrict__ W, unsigned short* __restrict__ Wt) {
    int idx = blockIdx.x * 256 + threadIdx.x;
    int n = idx >> 8, k = idx & 255;
    Wt[n * 256 + k] = f2bf(W[k * 256 + n]);
}

// C[M,256](bf16) = A[M,256](fp32) @ B, B as bf16 Bt[n][k].
// BM=64, 4 waves x 16 rows. A fragments direct from global (full-line
// coverage via the v0/v1 pair). C staged through LDS for coalesced stores.
__global__ __launch_bounds__(256) void k_gemm(const float* __restrict__ A,
                                              const unsigned short* __restrict__ Bt,
                                              unsigned short* __restrict__ Cb, int M) {
    __shared__ unsigned short sC[64][264];  // +8 pad; row stride 528B = 33*16B
    int t = threadIdx.x;
    int wave = t >> 6, lane = t & 63;
    int quad = lane >> 4, l16 = lane & 15;
    int bm = blockIdx.x * 64;

    int row = bm + wave * 16 + l16;
    if (row >= M) row = M - 1;  // clamp: loads in-bounds, stores masked later
    const float* ap = A + (size_t)row * D + quad * 8;

    short8 af[8];
#pragma unroll
    for (int k0 = 0; k0 < 8; ++k0) {
        f32x4 v0 = *reinterpret_cast<const f32x4*>(ap + k0 * 32);
        f32x4 v1 = *reinterpret_cast<const f32x4*>(ap + k0 * 32 + 4);
        short8 a;
        a[0] = (short)f2bf(v0.x); a[1] = (short)f2bf(v0.y);
        a[2] = (short)f2bf(v0.z); a[3] = (short)f2bf(v0.w);
        a[4] = (short)f2bf(v1.x); a[5] = (short)f2bf(v1.y);
        a[6] = (short)f2bf(v1.z); a[7] = (short)f2bf(v1.w);
        af[k0] = a;
    }

    f32x4 acc[16];
#pragma unroll
    for (int nt = 0; nt < 16; ++nt) acc[nt] = (f32x4){0.f, 0.f, 0.f, 0.f};

#pragma unroll 4
    for (int nt = 0; nt < 16; ++nt) {
        const unsigned short* bp = Bt + (size_t)(nt * 16 + l16) * D + quad * 8;
        short8 bf[8];
#pragma unroll
        for (int k0 = 0; k0 < 8; ++k0)
            bf[k0] = *reinterpret_cast<const short8*>(bp + k0 * 32);
#pragma unroll
        for (int k0 = 0; k0 < 8; ++k0)
            acc[nt] = __builtin_amdgcn_mfma_f32_16x16x32_bf16(af[k0], bf[k0], acc[nt], 0, 0, 0);
    }

    // acc -> LDS (bf16)
    int rbase = wave * 16 + quad * 4;
#pragma unroll
    for (int nt = 0; nt < 16; ++nt) {
#pragma unroll
        for (int r = 0; r < 4; ++r)
            sC[rbase + r][nt * 16 + l16] = f2bf(acc[nt][r]);
    }
    __syncthreads();

    // coalesced write: 64 rows x 32 chunks of 16B; 2048 chunks / 256 thr = 8 iters
#pragma unroll
    for (int it = 0; it < 8; ++it) {
        int idx = it * 256 + t;
        int r = idx >> 5, ch = idx & 31;
        int gr = bm + r;
        if (gr < M)
            *reinterpret_cast<uint4*>(Cb + (size_t)gr * D + ch * 8) =
                *reinterpret_cast<const uint4*>(&sC[r][ch * 8]);
    }
}

// one wave per node: bf16 gather-aggregate + bias + LayerNorm + ReLU -> fp32
__global__ __launch_bounds__(256) void k_agg(const unsigned short* __restrict__ hb,
                                             const int* __restrict__ offs,
                                             const int2* __restrict__ ew,
                                             const float* __restrict__ dinv,
                                             const float* __restrict__ bias,
                                             const float* __restrict__ lnw,
                                             const float* __restrict__ lnb,
                                             float* __restrict__ out, int n) {
    int wave = threadIdx.x >> 6, lane = threadIdx.x & 63;
    int node = blockIdx.x * 4 + wave;
    if (node >= n) return;
    float di = dinv[node];
    uint2 rs = *reinterpret_cast<const uint2*>(hb + (size_t)node * D + lane * 4);
    f32x4 acc = bf4_to_f32(rs) * (di * di);  // self-loop term
    int e0 = offs[node], e1 = offs[node + 1];
    int e = e0;
#pragma unroll 1
    for (; e + 4 <= e1; e += 4) {
        int2 p0 = ew[e + 0], p1 = ew[e + 1], p2 = ew[e + 2], p3 = ew[e + 3];
        uint2 r0 = *reinterpret_cast<const uint2*>(hb + (size_t)p0.x * D + lane * 4);
        uint2 r1 = *reinterpret_cast<const uint2*>(hb + (size_t)p1.x * D + lane * 4);
        uint2 r2 = *reinterpret_cast<const uint2*>(hb + (size_t)p2.x * D + lane * 4);
        uint2 r3 = *reinterpret_cast<const uint2*>(hb + (size_t)p3.x * D + lane * 4);
        acc += bf4_to_f32(r0) * (__builtin_bit_cast(float, p0.y) * di);
        acc += bf4_to_f32(r1) * (__builtin_bit_cast(float, p1.y) * di);
        acc += bf4_to_f32(r2) * (__builtin_bit_cast(float, p2.y) * di);
        acc += bf4_to_f32(r3) * (__builtin_bit_cast(float, p3.y) * di);
    }
    for (; e < e1; ++e) {
        int2 p = ew[e];
        uint2 r = *reinterpret_cast<const uint2*>(hb + (size_t)p.x * D + lane * 4);
        acc += bf4_to_f32(r) * (__builtin_bit_cast(float, p.y) * di);
    }
    acc += ((const f32x4*)bias)[lane];

    float s1 = acc.x + acc.y + acc.z + acc.w;
    float s2 = acc.x * acc.x + acc.y * acc.y + acc.z * acc.z + acc.w * acc.w;
#pragma unroll
    for (int o = 32; o > 0; o >>= 1) {
        s1 += __shfl_xor(s1, o, 64);
        s2 += __shfl_xor(s2, o, 64);
    }
    float mean = s1 * (1.0f / 256.0f);
    float var = s2 * (1.0f / 256.0f) - mean * mean;
    float inv = rsqrtf(var + 1e-5f);
    f32x4 w4 = ((const f32x4*)lnw)[lane];
    f32x4 lb = ((const f32x4*)lnb)[lane];
    f32x4 y;
    y.x = fmaxf((acc.x - mean) * inv * w4.x + lb.x, 0.f);
    y.y = fmaxf((acc.y - mean) * inv * w4.y + lb.y, 0.f);
    y.z = fmaxf((acc.z - mean) * inv * w4.z + lb.z, 0.f);
    y.w = fmaxf((acc.w - mean) * inv * w4.w + lb.w, 0.f);
    ((f32x4*)out)[(size_t)node * 64 + lane] = y;
}

// one block per graph: mean-pool (batch sorted -> binary search) + linear
__global__ __launch_bounds__(256) void k_pool(const float* __restrict__ h,
                                              const int* __restrict__ batch,
                                              const float* __restrict__ linW,
                                              const float* __restrict__ linb,
                                              float* __restrict__ out,
                                              int nNodes) {
    int g = blockIdx.x, t = threadIdx.x;
    int lo = 0, hi = nNodes;
    while (lo < hi) { int m = (lo + hi) >> 1; if (batch[m] < g) lo = m + 1; else hi = m; }
    int lo2 = lo, hi2 = nNodes;
    while (lo2 < hi2) { int m = (lo2 + hi2) >> 1; if (batch[m] < g + 1) lo2 = m + 1; else hi2 = m; }
    float s = 0.f;
    for (int i = lo; i < lo2; ++i) s += h[(size_t)i * D + t];
    float cnt = (float)(lo2 - lo);
    float pooled = s / fmaxf(cnt, 1.f);
    __shared__ float sp[256];
    __shared__ float red[4];
    sp[t] = pooled;
    __syncthreads();
    for (int c = 0; c < 10; ++c) {
        float v = sp[t] * linW[t * 10 + c];
#pragma unroll
        for (int o = 32; o > 0; o >>= 1) v += __shfl_xor(v, o, 64);
        if ((t & 63) == 0) red[t >> 6] = v;
        __syncthreads();
        if (t == 0) out[g * 10 + c] = red[0] + red[1] + red[2] + red[3] + linb[c];
        __syncthreads();
    }
}

extern "C" void kernel_launch(void* const* d_in, const int* in_sizes, int n_in,
                              void* d_out, int out_size, void* d_ws, size_t ws_size,
                              hipStream_t stream) {
    const float* x    = (const float*)d_in[0];
    const int*   ei   = (const int*)d_in[1];
    const int*   batch= (const int*)d_in[2];
    const float* W1   = (const float*)d_in[3];
    const float* b1   = (const float*)d_in[4];
    const float* W2   = (const float*)d_in[5];
    const float* b2   = (const float*)d_in[6];
    const float* ln1w = (const float*)d_in[7];
    const float* ln1b = (const float*)d_in[8];
    const float* ln2w = (const float*)d_in[9];
    const float* ln2b = (const float*)d_in[10];
    const float* linW = (const float*)d_in[11];
    const float* linb = (const float*)d_in[12];
    float* out = (float*)d_out;

    int nNodes  = in_sizes[0] / D;   // 50000
    int nEdges  = in_sizes[1] / 2;   // 800000
    int nGraphs = out_size / 10;     // 512

    const int* src = ei;
    const int* dst = ei + nEdges;

    char* ws = (char*)d_ws;
    size_t o = 0;
    auto alloc = [&](size_t bytes) -> char* {
        char* p = ws + o;
        o += (bytes + 511) & ~(size_t)511;
        return p;
    };
    unsigned short* hW = (unsigned short*)alloc((size_t)nNodes * D * 2);  // bf16 gather target
    float* h1  = (float*)alloc((size_t)nNodes * D * 4);                   // fp32 LN output
    int* deg   = (int*)alloc((size_t)nNodes * 4);
    int* cur   = (int*)alloc((size_t)nNodes * 4);
    int* offs  = (int*)alloc((size_t)(nNodes + 1) * 4);
    int2* ew   = (int2*)alloc((size_t)nEdges * 8);
    float* dinv= (float*)alloc((size_t)nNodes * 4);
    int* bsum  = (int*)alloc(256 * 4);
    unsigned short* Wt = (unsigned short*)alloc((size_t)D * D * 2);
    (void)ws_size;

    int gn = (nNodes + 255) / 256;   // 196 blocks
    int ge = (nEdges + 255) / 256;

    // CSR build (dst counting sort; hierarchical scan; per-edge weight fused)
    k_zero2<<<gn, 256, 0, stream>>>(deg, cur, nNodes);
    k_deg  <<<ge, 256, 0, stream>>>(dst, deg, nEdges);
    k_scan1<<<gn, 256, 0, stream>>>(deg, dinv, bsum, nNodes);
    k_scan2<<<1, 256, 0, stream>>>(bsum, offs, gn, nNodes);
    k_scan3<<<gn, 256, 0, stream>>>(deg, bsum, offs, nNodes);
    k_fill <<<ge, 256, 0, stream>>>(src, dst, offs, cur, dinv, ew, nEdges);

    // layer 1
    k_wt  <<<D, 256, 0, stream>>>(W1, Wt);
    k_gemm<<<(nNodes + 63) / 64, 256, 0, stream>>>(x, Wt, hW, nNodes);
    k_agg <<<(nNodes + 3) / 4, 256, 0, stream>>>(hW, offs, ew, dinv, b1, ln1w, ln1b, h1, nNodes);

    // layer 2
    k_wt  <<<D, 256, 0, stream>>>(W2, Wt);
    k_gemm<<<(nNodes + 63) / 64, 256, 0, stream>>>(h1, Wt, hW, nNodes);
    k_agg <<<(nNodes + 3) / 4, 256, 0, stream>>>(hW, offs, ew, dinv, b2, ln2w, ln2b, h1, nNodes);

    // pool + classifier
    k_pool<<<nGraphs, 256, 0, stream>>>(h1, batch, linW, linb, out, nNodes);
}

// Round 4
// 431.588 us; speedup vs baseline: 1.7189x; 1.2653x over previous
//
#include <hip/hip_runtime.h>
#include <stdint.h>

#define D 256
#define TPB 256

typedef __attribute__((ext_vector_type(8))) short short8;
typedef __attribute__((ext_vector_type(4))) float f32x4;

__device__ inline unsigned short f2bf(float f) {
    uint32_t u = __builtin_bit_cast(uint32_t, f);
    uint32_t r = (u + 0x7FFFu + ((u >> 16) & 1u)) >> 16;  // RNE
    return (unsigned short)r;
}

__device__ inline float bf2f(unsigned short b) {
    return __builtin_bit_cast(float, (uint32_t)b << 16);
}

__device__ inline f32x4 bf4_to_f32(uint2 v) {
    f32x4 r;
    r.x = __builtin_bit_cast(float, v.x << 16);
    r.y = __builtin_bit_cast(float, v.x & 0xFFFF0000u);
    r.z = __builtin_bit_cast(float, v.y << 16);
    r.w = __builtin_bit_cast(float, v.y & 0xFFFF0000u);
    return r;
}

__global__ void k_zero2(int* __restrict__ a, int* __restrict__ b, int n) {
    int i = blockIdx.x * blockDim.x + threadIdx.x;
    if (i < n) { a[i] = 0; b[i] = 0; }
}

__global__ void k_deg(const int* __restrict__ dst, int* __restrict__ deg, int ne) {
    int i = blockIdx.x * blockDim.x + threadIdx.x;
    if (i < ne) atomicAdd(&deg[dst[i]], 1);
}

// fp32 -> bf16 cast, 8 elems/thread
__global__ __launch_bounds__(256) void k_f2b(const float* __restrict__ A,
                                             unsigned short* __restrict__ B, int n8) {
    int i = blockIdx.x * 256 + threadIdx.x;
    if (i < n8) {
        f32x4 v0 = ((const f32x4*)A)[i * 2];
        f32x4 v1 = ((const f32x4*)A)[i * 2 + 1];
        short8 o;
        o[0] = (short)f2bf(v0.x); o[1] = (short)f2bf(v0.y);
        o[2] = (short)f2bf(v0.z); o[3] = (short)f2bf(v0.w);
        o[4] = (short)f2bf(v1.x); o[5] = (short)f2bf(v1.y);
        o[6] = (short)f2bf(v1.z); o[7] = (short)f2bf(v1.w);
        ((short8*)B)[i] = o;
    }
}

// phase 1: per-block sum of deg (coalesced) + dinv
__global__ __launch_bounds__(256) void k_scan1(const int* __restrict__ deg,
                                               float* __restrict__ dinv,
                                               int* __restrict__ bsum, int n) {
    int t = threadIdx.x, i = blockIdx.x * 256 + t;
    int d = 0;
    if (i < n) {
        d = deg[i];
        dinv[i] = rsqrtf((float)(d + 1));  // +1 self-loop, always > 0
    }
    int s = d;
#pragma unroll
    for (int o = 32; o > 0; o >>= 1) s += __shfl_xor(s, o, 64);
    __shared__ int red[4];
    if ((t & 63) == 0) red[t >> 6] = s;
    __syncthreads();
    if (t == 0) bsum[blockIdx.x] = red[0] + red[1] + red[2] + red[3];
}

// phase 2: single block, exclusive scan of bsum[nb] (nb<=256); offs[n]=total
__global__ __launch_bounds__(256) void k_scan2(int* __restrict__ bsum,
                                               int* __restrict__ offs, int nb, int n) {
    __shared__ int sh[256];
    int t = threadIdx.x;
    int v = (t < nb) ? bsum[t] : 0;
    sh[t] = v;
    __syncthreads();
#pragma unroll
    for (int o = 1; o < 256; o <<= 1) {
        int u = (t >= o) ? sh[t - o] : 0;
        __syncthreads();
        sh[t] += u;
        __syncthreads();
    }
    if (t < nb) bsum[t] = sh[t] - v;    // exclusive base per block
    if (t == 0) offs[n] = sh[255];      // total
}

// phase 3: per-block exclusive scan of its 256 deg elems + base -> offs
__global__ __launch_bounds__(256) void k_scan3(const int* __restrict__ deg,
                                               const int* __restrict__ bsum,
                                               int* __restrict__ offs, int n) {
    int t = threadIdx.x, i = blockIdx.x * 256 + t;
    int d = (i < n) ? deg[i] : 0;
    __shared__ int sh[256];
    sh[t] = d;
    __syncthreads();
#pragma unroll
    for (int o = 1; o < 256; o <<= 1) {
        int u = (t >= o) ? sh[t - o] : 0;
        __syncthreads();
        sh[t] += u;
        __syncthreads();
    }
    if (i < n) offs[i] = bsum[blockIdx.x] + sh[t] - d;
}

// CSR fill with fused per-edge weight: ew[e] = (src, bits(dinv[src]))
__global__ void k_fill(const int* __restrict__ src, const int* __restrict__ dst,
                       const int* __restrict__ offs, int* __restrict__ cur,
                       const float* __restrict__ dinv, int2* __restrict__ ew, int ne) {
    int i = blockIdx.x * blockDim.x + threadIdx.x;
    if (i < ne) {
        int s = src[i], d = dst[i];
        int p = atomicAdd(&cur[d], 1);
        int2 e;
        e.x = s;
        e.y = __builtin_bit_cast(int, dinv[s]);
        ew[offs[d] + p] = e;
    }
}

// Wt[n][k] = bf16(W[k][n])  (W is 256x256 row-major KxN)
__global__ void k_wt(const float* __restrict__ W, unsigned short* __restrict__ Wt) {
    int idx = blockIdx.x * 256 + threadIdx.x;
    int n = idx >> 8, k = idx & 255;
    Wt[n * 256 + k] = f2bf(W[k * 256 + n]);
}

// C[M,256](bf16) = A[M,256](bf16) @ B, B as bf16 Bt[n][k].
// 4 waves in 2x2; each wave computes 64x64 via 4x4 accs. Per k-step:
// 8 independent 16B loads feed 16 independent MFMAs (latency hiding via ILP).
__global__ __launch_bounds__(256, 4) void k_gemm(const unsigned short* __restrict__ A,
                                                 const unsigned short* __restrict__ Bt,
                                                 unsigned short* __restrict__ Cb, int M) {
    __shared__ unsigned short sC[128][136];  // 128x128 tile, +8 pad; row=272B (16B-aligned)
    int t = threadIdx.x;
    int wave = t >> 6, lane = t & 63;
    int quad = lane >> 4, l16 = lane & 15;
    int mr = wave >> 1, nc = wave & 1;
    int bm = blockIdx.x * 128;
    int bn = blockIdx.y * 128;

    const unsigned short* aptr[4];
#pragma unroll
    for (int tm = 0; tm < 4; ++tm) {
        int row = bm + mr * 64 + tm * 16 + l16;
        if (row >= M) row = M - 1;  // clamp: loads in-bounds, stores masked later
        aptr[tm] = A + (size_t)row * D + quad * 8;
    }
    const unsigned short* bptr[4];
#pragma unroll
    for (int tn = 0; tn < 4; ++tn) {
        int col = bn + nc * 64 + tn * 16 + l16;
        bptr[tn] = Bt + (size_t)col * D + quad * 8;
    }

    f32x4 acc[4][4];
#pragma unroll
    for (int tm = 0; tm < 4; ++tm)
#pragma unroll
        for (int tn = 0; tn < 4; ++tn) acc[tm][tn] = (f32x4){0.f, 0.f, 0.f, 0.f};

#pragma unroll 2
    for (int ks = 0; ks < 8; ++ks) {
        int ko = ks * 32;
        short8 a[4], b[4];
#pragma unroll
        for (int tm = 0; tm < 4; ++tm) a[tm] = *reinterpret_cast<const short8*>(aptr[tm] + ko);
#pragma unroll
        for (int tn = 0; tn < 4; ++tn) b[tn] = *reinterpret_cast<const short8*>(bptr[tn] + ko);
#pragma unroll
        for (int tm = 0; tm < 4; ++tm)
#pragma unroll
            for (int tn = 0; tn < 4; ++tn)
                acc[tm][tn] = __builtin_amdgcn_mfma_f32_16x16x32_bf16(a[tm], b[tn], acc[tm][tn], 0, 0, 0);
    }

    // acc -> LDS (bf16)
#pragma unroll
    for (int tm = 0; tm < 4; ++tm) {
        int rb = mr * 64 + tm * 16 + quad * 4;
#pragma unroll
        for (int tn = 0; tn < 4; ++tn) {
            int cc = nc * 64 + tn * 16 + l16;
#pragma unroll
            for (int r = 0; r < 4; ++r)
                sC[rb + r][cc] = f2bf(acc[tm][tn][r]);
        }
    }
    __syncthreads();

    // coalesced write: 128 rows x 16 chunks of 16B; 2048 chunks / 256 thr
#pragma unroll
    for (int it = 0; it < 8; ++it) {
        int idx = it * 256 + t;
        int r = idx >> 4, ch = idx & 15;
        int gr = bm + r;
        if (gr < M)
            *reinterpret_cast<uint4*>(Cb + (size_t)gr * D + bn + ch * 8) =
                *reinterpret_cast<const uint4*>(&sC[r][ch * 8]);
    }
}

// one wave per node: bf16 gather-aggregate + bias + LayerNorm + ReLU -> bf16
__global__ __launch_bounds__(256) void k_agg(const unsigned short* __restrict__ hb,
                                             const int* __restrict__ offs,
                                             const int2* __restrict__ ew,
                                             const float* __restrict__ dinv,
                                             const float* __restrict__ bias,
                                             const float* __restrict__ lnw,
                                             const float* __restrict__ lnb,
                                             unsigned short* __restrict__ out, int n) {
    int wave = threadIdx.x >> 6, lane = threadIdx.x & 63;
    int node = blockIdx.x * 4 + wave;
    if (node >= n) return;
    float di = dinv[node];
    uint2 rs = *reinterpret_cast<const uint2*>(hb + (size_t)node * D + lane * 4);
    f32x4 acc = bf4_to_f32(rs) * (di * di);  // self-loop term
    int e0 = offs[node], e1 = offs[node + 1];
    int e = e0;
#pragma unroll 1
    for (; e + 4 <= e1; e += 4) {
        int2 p0 = ew[e + 0], p1 = ew[e + 1], p2 = ew[e + 2], p3 = ew[e + 3];
        uint2 r0 = *reinterpret_cast<const uint2*>(hb + (size_t)p0.x * D + lane * 4);
        uint2 r1 = *reinterpret_cast<const uint2*>(hb + (size_t)p1.x * D + lane * 4);
        uint2 r2 = *reinterpret_cast<const uint2*>(hb + (size_t)p2.x * D + lane * 4);
        uint2 r3 = *reinterpret_cast<const uint2*>(hb + (size_t)p3.x * D + lane * 4);
        acc += bf4_to_f32(r0) * (__builtin_bit_cast(float, p0.y) * di);
        acc += bf4_to_f32(r1) * (__builtin_bit_cast(float, p1.y) * di);
        acc += bf4_to_f32(r2) * (__builtin_bit_cast(float, p2.y) * di);
        acc += bf4_to_f32(r3) * (__builtin_bit_cast(float, p3.y) * di);
    }
    for (; e < e1; ++e) {
        int2 p = ew[e];
        uint2 r = *reinterpret_cast<const uint2*>(hb + (size_t)p.x * D + lane * 4);
        acc += bf4_to_f32(r) * (__builtin_bit_cast(float, p.y) * di);
    }
    acc += ((const f32x4*)bias)[lane];

    float s1 = acc.x + acc.y + acc.z + acc.w;
    float s2 = acc.x * acc.x + acc.y * acc.y + acc.z * acc.z + acc.w * acc.w;
#pragma unroll
    for (int o = 32; o > 0; o >>= 1) {
        s1 += __shfl_xor(s1, o, 64);
        s2 += __shfl_xor(s2, o, 64);
    }
    float mean = s1 * (1.0f / 256.0f);
    float var = s2 * (1.0f / 256.0f) - mean * mean;
    float inv = rsqrtf(var + 1e-5f);
    f32x4 w4 = ((const f32x4*)lnw)[lane];
    f32x4 lb = ((const f32x4*)lnb)[lane];
    float y0 = fmaxf((acc.x - mean) * inv * w4.x + lb.x, 0.f);
    float y1 = fmaxf((acc.y - mean) * inv * w4.y + lb.y, 0.f);
    float y2 = fmaxf((acc.z - mean) * inv * w4.z + lb.z, 0.f);
    float y3 = fmaxf((acc.w - mean) * inv * w4.w + lb.w, 0.f);
    uint2 w;
    w.x = (uint32_t)f2bf(y0) | ((uint32_t)f2bf(y1) << 16);
    w.y = (uint32_t)f2bf(y2) | ((uint32_t)f2bf(y3) << 16);
    *reinterpret_cast<uint2*>(out + (size_t)node * D + lane * 4) = w;
}

// one block per graph: mean-pool (batch sorted -> binary search) + linear
__global__ __launch_bounds__(256) void k_pool(const unsigned short* __restrict__ h,
                                              const int* __restrict__ batch,
                                              const float* __restrict__ linW,
                                              const float* __restrict__ linb,
                                              float* __restrict__ out,
                                              int nNodes) {
    int g = blockIdx.x, t = threadIdx.x;
    int lo = 0, hi = nNodes;
    while (lo < hi) { int m = (lo + hi) >> 1; if (batch[m] < g) lo = m + 1; else hi = m; }
    int lo2 = lo, hi2 = nNodes;
    while (lo2 < hi2) { int m = (lo2 + hi2) >> 1; if (batch[m] < g + 1) lo2 = m + 1; else hi2 = m; }
    float s = 0.f;
    for (int i = lo; i < lo2; ++i) s += bf2f(h[(size_t)i * D + t]);
    float cnt = (float)(lo2 - lo);
    float pooled = s / fmaxf(cnt, 1.f);
    __shared__ float sp[256];
    __shared__ float red[4];
    sp[t] = pooled;
    __syncthreads();
    for (int c = 0; c < 10; ++c) {
        float v = sp[t] * linW[t * 10 + c];
#pragma unroll
        for (int o = 32; o > 0; o >>= 1) v += __shfl_xor(v, o, 64);
        if ((t & 63) == 0) red[t >> 6] = v;
        __syncthreads();
        if (t == 0) out[g * 10 + c] = red[0] + red[1] + red[2] + red[3] + linb[c];
        __syncthreads();
    }
}

extern "C" void kernel_launch(void* const* d_in, const int* in_sizes, int n_in,
                              void* d_out, int out_size, void* d_ws, size_t ws_size,
                              hipStream_t stream) {
    const float* x    = (const float*)d_in[0];
    const int*   ei   = (const int*)d_in[1];
    const int*   batch= (const int*)d_in[2];
    const float* W1   = (const float*)d_in[3];
    const float* b1   = (const float*)d_in[4];
    const float* W2   = (const float*)d_in[5];
    const float* b2   = (const float*)d_in[6];
    const float* ln1w = (const float*)d_in[7];
    const float* ln1b = (const float*)d_in[8];
    const float* ln2w = (const float*)d_in[9];
    const float* ln2b = (const float*)d_in[10];
    const float* linW = (const float*)d_in[11];
    const float* linb = (const float*)d_in[12];
    float* out = (float*)d_out;

    int nNodes  = in_sizes[0] / D;   // 50000
    int nEdges  = in_sizes[1] / 2;   // 800000
    int nGraphs = out_size / 10;     // 512

    const int* src = ei;
    const int* dst = ei + nEdges;

    char* ws = (char*)d_ws;
    size_t o = 0;
    auto alloc = [&](size_t bytes) -> char* {
        char* p = ws + o;
        o += (bytes + 511) & ~(size_t)511;
        return p;
    };
    unsigned short* xb = (unsigned short*)alloc((size_t)nNodes * D * 2);  // bf16 x / h2
    unsigned short* hW = (unsigned short*)alloc((size_t)nNodes * D * 2);  // bf16 gemm out
    unsigned short* h1 = (unsigned short*)alloc((size_t)nNodes * D * 2);  // bf16 LN out
    int* deg   = (int*)alloc((size_t)nNodes * 4);
    int* cur   = (int*)alloc((size_t)nNodes * 4);
    int* offs  = (int*)alloc((size_t)(nNodes + 1) * 4);
    int2* ew   = (int2*)alloc((size_t)nEdges * 8);
    float* dinv= (float*)alloc((size_t)nNodes * 4);
    int* bsum  = (int*)alloc(256 * 4);
    unsigned short* Wt = (unsigned short*)alloc((size_t)D * D * 2);
    (void)ws_size;

    int gn = (nNodes + 255) / 256;   // 196 blocks
    int ge = (nEdges + 255) / 256;
    dim3 ggemm((nNodes + 127) / 128, 2);

    // CSR build (dst counting sort; hierarchical scan; per-edge weight fused)
    k_zero2<<<gn, 256, 0, stream>>>(deg, cur, nNodes);
    k_deg  <<<ge, 256, 0, stream>>>(dst, deg, nEdges);
    k_scan1<<<gn, 256, 0, stream>>>(deg, dinv, bsum, nNodes);
    k_scan2<<<1, 256, 0, stream>>>(bsum, offs, gn, nNodes);
    k_scan3<<<gn, 256, 0, stream>>>(deg, bsum, offs, nNodes);
    k_fill <<<ge, 256, 0, stream>>>(src, dst, offs, cur, dinv, ew, nEdges);

    // x -> bf16
    k_f2b<<<(nNodes * 32 + 255) / 256, 256, 0, stream>>>(x, xb, nNodes * 32);

    // layer 1
    k_wt  <<<D, 256, 0, stream>>>(W1, Wt);
    k_gemm<<<ggemm, 256, 0, stream>>>(xb, Wt, hW, nNodes);
    k_agg <<<(nNodes + 3) / 4, 256, 0, stream>>>(hW, offs, ew, dinv, b1, ln1w, ln1b, h1, nNodes);

    // layer 2 (reuse xb as h2)
    k_wt  <<<D, 256, 0, stream>>>(W2, Wt);
    k_gemm<<<ggemm, 256, 0, stream>>>(h1, Wt, hW, nNodes);
    k_agg <<<(nNodes + 3) / 4, 256, 0, stream>>>(hW, offs, ew, dinv, b2, ln2w, ln2b, xb, nNodes);

    // pool + classifier
    k_pool<<<nGraphs, 256, 0, stream>>>(xb, batch, linW, linb, out, nNodes);
}

// Round 5
// 407.091 us; speedup vs baseline: 1.8223x; 1.0602x over previous
//
#include <hip/hip_runtime.h>
#include <stdint.h>

#define D 256
#define TPB 256

typedef __attribute__((ext_vector_type(8))) short short8;
typedef __attribute__((ext_vector_type(4))) float f32x4;

__device__ inline unsigned short f2bf(float f) {
    uint32_t u = __builtin_bit_cast(uint32_t, f);
    uint32_t r = (u + 0x7FFFu + ((u >> 16) & 1u)) >> 16;  // RNE
    return (unsigned short)r;
}

__device__ inline float bf2f(unsigned short b) {
    return __builtin_bit_cast(float, (uint32_t)b << 16);
}

__device__ inline f32x4 bf4_to_f32(uint2 v) {
    f32x4 r;
    r.x = __builtin_bit_cast(float, v.x << 16);
    r.y = __builtin_bit_cast(float, v.x & 0xFFFF0000u);
    r.z = __builtin_bit_cast(float, v.y << 16);
    r.w = __builtin_bit_cast(float, v.y & 0xFFFF0000u);
    return r;
}

__global__ void k_zero2(int* __restrict__ a, int* __restrict__ b, int n) {
    int i = blockIdx.x * blockDim.x + threadIdx.x;
    if (i < n) { a[i] = 0; b[i] = 0; }
}

__global__ void k_deg(const int* __restrict__ dst, int* __restrict__ deg, int ne) {
    int i = blockIdx.x * blockDim.x + threadIdx.x;
    if (i < ne) atomicAdd(&deg[dst[i]], 1);
}

// fused prep: blocks [0, nf2b) cast x->bf16 (8 elems/thread);
// blocks [nf2b, nf2b+512) transpose+cast W1,W2 -> Wt1,Wt2
__global__ __launch_bounds__(256) void k_prep(const float* __restrict__ x,
                                              unsigned short* __restrict__ xb, int n8,
                                              const float* __restrict__ W1,
                                              const float* __restrict__ W2,
                                              unsigned short* __restrict__ Wt1,
                                              unsigned short* __restrict__ Wt2,
                                              int nf2b) {
    int b = blockIdx.x, t = threadIdx.x;
    if (b < nf2b) {
        int i = b * 256 + t;
        if (i < n8) {
            f32x4 v0 = ((const f32x4*)x)[i * 2];
            f32x4 v1 = ((const f32x4*)x)[i * 2 + 1];
            short8 o;
            o[0] = (short)f2bf(v0.x); o[1] = (short)f2bf(v0.y);
            o[2] = (short)f2bf(v0.z); o[3] = (short)f2bf(v0.w);
            o[4] = (short)f2bf(v1.x); o[5] = (short)f2bf(v1.y);
            o[6] = (short)f2bf(v1.z); o[7] = (short)f2bf(v1.w);
            ((short8*)xb)[i] = o;
        }
    } else {
        int idx = (b - nf2b) * 256 + t;       // [0, 131072)
        int w = idx >> 16;                    // 0 -> W1, 1 -> W2
        int r = idx & 65535;
        int n = r >> 8, k = r & 255;
        const float* W = w ? W2 : W1;
        unsigned short* Wt = w ? Wt2 : Wt1;
        Wt[n * 256 + k] = f2bf(W[k * 256 + n]);
    }
}

// phase 1: per-block sum of deg (coalesced) + dinv
__global__ __launch_bounds__(256) void k_scan1(const int* __restrict__ deg,
                                               float* __restrict__ dinv,
                                               int* __restrict__ bsum, int n) {
    int t = threadIdx.x, i = blockIdx.x * 256 + t;
    int d = 0;
    if (i < n) {
        d = deg[i];
        dinv[i] = rsqrtf((float)(d + 1));  // +1 self-loop, always > 0
    }
    int s = d;
#pragma unroll
    for (int o = 32; o > 0; o >>= 1) s += __shfl_xor(s, o, 64);
    __shared__ int red[4];
    if ((t & 63) == 0) red[t >> 6] = s;
    __syncthreads();
    if (t == 0) bsum[blockIdx.x] = red[0] + red[1] + red[2] + red[3];
}

// phase 2: single block, exclusive scan of bsum[nb] (nb<=256); offs[n]=total
__global__ __launch_bounds__(256) void k_scan2(int* __restrict__ bsum,
                                               int* __restrict__ offs, int nb, int n) {
    __shared__ int sh[256];
    int t = threadIdx.x;
    int v = (t < nb) ? bsum[t] : 0;
    sh[t] = v;
    __syncthreads();
#pragma unroll
    for (int o = 1; o < 256; o <<= 1) {
        int u = (t >= o) ? sh[t - o] : 0;
        __syncthreads();
        sh[t] += u;
        __syncthreads();
    }
    if (t < nb) bsum[t] = sh[t] - v;    // exclusive base per block
    if (t == 0) offs[n] = sh[255];      // total
}

// phase 3: per-block exclusive scan of its 256 deg elems + base -> offs
__global__ __launch_bounds__(256) void k_scan3(const int* __restrict__ deg,
                                               const int* __restrict__ bsum,
                                               int* __restrict__ offs, int n) {
    int t = threadIdx.x, i = blockIdx.x * 256 + t;
    int d = (i < n) ? deg[i] : 0;
    __shared__ int sh[256];
    sh[t] = d;
    __syncthreads();
#pragma unroll
    for (int o = 1; o < 256; o <<= 1) {
        int u = (t >= o) ? sh[t - o] : 0;
        __syncthreads();
        sh[t] += u;
        __syncthreads();
    }
    if (i < n) offs[i] = bsum[blockIdx.x] + sh[t] - d;
}

// CSR fill with fused per-edge weight: ew[e] = (src, bits(dinv[src]))
__global__ void k_fill(const int* __restrict__ src, const int* __restrict__ dst,
                       const int* __restrict__ offs, int* __restrict__ cur,
                       const float* __restrict__ dinv, int2* __restrict__ ew, int ne) {
    int i = blockIdx.x * blockDim.x + threadIdx.x;
    if (i < ne) {
        int s = src[i], d = dst[i];
        int p = atomicAdd(&cur[d], 1);
        int2 e;
        e.x = s;
        e.y = __builtin_bit_cast(int, dinv[s]);
        ew[offs[d] + p] = e;
    }
}

// C[M,256](bf16) = A[M,256](bf16) @ B, B as bf16 Bt[n][k].
// 4 waves in 2x2; each wave computes 64x64 via 4x4 accs. 1-D grid with
// paired (bm,bn): consecutive blocks share the A-tile (L2 reuse).
__global__ __launch_bounds__(256, 4) void k_gemm(const unsigned short* __restrict__ A,
                                                 const unsigned short* __restrict__ Bt,
                                                 unsigned short* __restrict__ Cb, int M) {
    __shared__ unsigned short sC[128][136];  // 128x128 tile, +8 pad
    int t = threadIdx.x;
    int wave = t >> 6, lane = t & 63;
    int quad = lane >> 4, l16 = lane & 15;
    int mr = wave >> 1, nc = wave & 1;
    int bm = (blockIdx.x >> 1) * 128;
    int bn = (blockIdx.x & 1) * 128;

    const unsigned short* aptr[4];
#pragma unroll
    for (int tm = 0; tm < 4; ++tm) {
        int row = bm + mr * 64 + tm * 16 + l16;
        if (row >= M) row = M - 1;  // clamp: loads in-bounds, stores masked later
        aptr[tm] = A + (size_t)row * D + quad * 8;
    }
    const unsigned short* bptr[4];
#pragma unroll
    for (int tn = 0; tn < 4; ++tn) {
        int col = bn + nc * 64 + tn * 16 + l16;
        bptr[tn] = Bt + (size_t)col * D + quad * 8;
    }

    f32x4 acc[4][4];
#pragma unroll
    for (int tm = 0; tm < 4; ++tm)
#pragma unroll
        for (int tn = 0; tn < 4; ++tn) acc[tm][tn] = (f32x4){0.f, 0.f, 0.f, 0.f};

#pragma unroll 2
    for (int ks = 0; ks < 8; ++ks) {
        int ko = ks * 32;
        short8 a[4], b[4];
#pragma unroll
        for (int tm = 0; tm < 4; ++tm) a[tm] = *reinterpret_cast<const short8*>(aptr[tm] + ko);
#pragma unroll
        for (int tn = 0; tn < 4; ++tn) b[tn] = *reinterpret_cast<const short8*>(bptr[tn] + ko);
#pragma unroll
        for (int tm = 0; tm < 4; ++tm)
#pragma unroll
            for (int tn = 0; tn < 4; ++tn)
                acc[tm][tn] = __builtin_amdgcn_mfma_f32_16x16x32_bf16(a[tm], b[tn], acc[tm][tn], 0, 0, 0);
    }

    // acc -> LDS (bf16)
#pragma unroll
    for (int tm = 0; tm < 4; ++tm) {
        int rb = mr * 64 + tm * 16 + quad * 4;
#pragma unroll
        for (int tn = 0; tn < 4; ++tn) {
            int cc = nc * 64 + tn * 16 + l16;
#pragma unroll
            for (int r = 0; r < 4; ++r)
                sC[rb + r][cc] = f2bf(acc[tm][tn][r]);
        }
    }
    __syncthreads();

    // coalesced write: 128 rows x 16 chunks of 16B
#pragma unroll
    for (int it = 0; it < 8; ++it) {
        int idx = it * 256 + t;
        int r = idx >> 4, ch = idx & 15;
        int gr = bm + r;
        if (gr < M)
            *reinterpret_cast<uint4*>(Cb + (size_t)gr * D + bn + ch * 8) =
                *reinterpret_cast<const uint4*>(&sC[r][ch * 8]);
    }
}

// one wave per node: pipelined bf16 gather-aggregate + bias + LN + ReLU -> bf16
__global__ __launch_bounds__(256) void k_agg(const unsigned short* __restrict__ hb,
                                             const int* __restrict__ offs,
                                             const int2* __restrict__ ew,
                                             const float* __restrict__ dinv,
                                             const float* __restrict__ bias,
                                             const float* __restrict__ lnw,
                                             const float* __restrict__ lnb,
                                             unsigned short* __restrict__ out, int n) {
    int wave = threadIdx.x >> 6, lane = threadIdx.x & 63;
    int node = blockIdx.x * 4 + wave;
    if (node >= n) return;
    float di = dinv[node];
    uint2 rs = *reinterpret_cast<const uint2*>(hb + (size_t)node * D + lane * 4);
    f32x4 acc = bf4_to_f32(rs) * (di * di);  // self-loop term
    int e0 = offs[node], e1 = offs[node + 1];
    int e = e0;
    int2 p0, p1, p2, p3;
    if (e + 4 <= e1) {
        p0 = ew[e]; p1 = ew[e + 1]; p2 = ew[e + 2]; p3 = ew[e + 3];
    }
    // pipelined: next quad's ew loads issue while current quad's gathers fly
#pragma unroll 1
    for (; e + 8 <= e1; e += 4) {
        int2 q0 = ew[e + 4], q1 = ew[e + 5], q2 = ew[e + 6], q3 = ew[e + 7];
        uint2 r0 = *reinterpret_cast<const uint2*>(hb + (size_t)p0.x * D + lane * 4);
        uint2 r1 = *reinterpret_cast<const uint2*>(hb + (size_t)p1.x * D + lane * 4);
        uint2 r2 = *reinterpret_cast<const uint2*>(hb + (size_t)p2.x * D + lane * 4);
        uint2 r3 = *reinterpret_cast<const uint2*>(hb + (size_t)p3.x * D + lane * 4);
        acc += bf4_to_f32(r0) * (__builtin_bit_cast(float, p0.y) * di);
        acc += bf4_to_f32(r1) * (__builtin_bit_cast(float, p1.y) * di);
        acc += bf4_to_f32(r2) * (__builtin_bit_cast(float, p2.y) * di);
        acc += bf4_to_f32(r3) * (__builtin_bit_cast(float, p3.y) * di);
        p0 = q0; p1 = q1; p2 = q2; p3 = q3;
    }
    if (e + 4 <= e1) {
        uint2 r0 = *reinterpret_cast<const uint2*>(hb + (size_t)p0.x * D + lane * 4);
        uint2 r1 = *reinterpret_cast<const uint2*>(hb + (size_t)p1.x * D + lane * 4);
        uint2 r2 = *reinterpret_cast<const uint2*>(hb + (size_t)p2.x * D + lane * 4);
        uint2 r3 = *reinterpret_cast<const uint2*>(hb + (size_t)p3.x * D + lane * 4);
        acc += bf4_to_f32(r0) * (__builtin_bit_cast(float, p0.y) * di);
        acc += bf4_to_f32(r1) * (__builtin_bit_cast(float, p1.y) * di);
        acc += bf4_to_f32(r2) * (__builtin_bit_cast(float, p2.y) * di);
        acc += bf4_to_f32(r3) * (__builtin_bit_cast(float, p3.y) * di);
        e += 4;
    }
    for (; e < e1; ++e) {
        int2 p = ew[e];
        uint2 r = *reinterpret_cast<const uint2*>(hb + (size_t)p.x * D + lane * 4);
        acc += bf4_to_f32(r) * (__builtin_bit_cast(float, p.y) * di);
    }
    acc += ((const f32x4*)bias)[lane];

    float s1 = acc.x + acc.y + acc.z + acc.w;
    float s2 = acc.x * acc.x + acc.y * acc.y + acc.z * acc.z + acc.w * acc.w;
#pragma unroll
    for (int o = 32; o > 0; o >>= 1) {
        s1 += __shfl_xor(s1, o, 64);
        s2 += __shfl_xor(s2, o, 64);
    }
    float mean = s1 * (1.0f / 256.0f);
    float var = s2 * (1.0f / 256.0f) - mean * mean;
    float inv = rsqrtf(var + 1e-5f);
    f32x4 w4 = ((const f32x4*)lnw)[lane];
    f32x4 lb = ((const f32x4*)lnb)[lane];
    float y0 = fmaxf((acc.x - mean) * inv * w4.x + lb.x, 0.f);
    float y1 = fmaxf((acc.y - mean) * inv * w4.y + lb.y, 0.f);
    float y2 = fmaxf((acc.z - mean) * inv * w4.z + lb.z, 0.f);
    float y3 = fmaxf((acc.w - mean) * inv * w4.w + lb.w, 0.f);
    uint2 w;
    w.x = (uint32_t)f2bf(y0) | ((uint32_t)f2bf(y1) << 16);
    w.y = (uint32_t)f2bf(y2) | ((uint32_t)f2bf(y3) << 16);
    *reinterpret_cast<uint2*>(out + (size_t)node * D + lane * 4) = w;
}

// one block per graph: mean-pool (batch sorted -> binary search) + linear
__global__ __launch_bounds__(256) void k_pool(const unsigned short* __restrict__ h,
                                              const int* __restrict__ batch,
                                              const float* __restrict__ linW,
                                              const float* __restrict__ linb,
                                              float* __restrict__ out,
                                              int nNodes) {
    int g = blockIdx.x, t = threadIdx.x;
    int lo = 0, hi = nNodes;
    while (lo < hi) { int m = (lo + hi) >> 1; if (batch[m] < g) lo = m + 1; else hi = m; }
    int lo2 = lo, hi2 = nNodes;
    while (lo2 < hi2) { int m = (lo2 + hi2) >> 1; if (batch[m] < g + 1) lo2 = m + 1; else hi2 = m; }
    float s0 = 0.f, s1 = 0.f, s2 = 0.f, s3 = 0.f;
    int i = lo;
    for (; i + 4 <= lo2; i += 4) {
        s0 += bf2f(h[(size_t)(i + 0) * D + t]);
        s1 += bf2f(h[(size_t)(i + 1) * D + t]);
        s2 += bf2f(h[(size_t)(i + 2) * D + t]);
        s3 += bf2f(h[(size_t)(i + 3) * D + t]);
    }
    for (; i < lo2; ++i) s0 += bf2f(h[(size_t)i * D + t]);
    float s = (s0 + s1) + (s2 + s3);
    float cnt = (float)(lo2 - lo);
    float pooled = s / fmaxf(cnt, 1.f);
    __shared__ float sp[256];
    __shared__ float red[4];
    sp[t] = pooled;
    __syncthreads();
    for (int c = 0; c < 10; ++c) {
        float v = sp[t] * linW[t * 10 + c];
#pragma unroll
        for (int o = 32; o > 0; o >>= 1) v += __shfl_xor(v, o, 64);
        if ((t & 63) == 0) red[t >> 6] = v;
        __syncthreads();
        if (t == 0) out[g * 10 + c] = red[0] + red[1] + red[2] + red[3] + linb[c];
        __syncthreads();
    }
}

extern "C" void kernel_launch(void* const* d_in, const int* in_sizes, int n_in,
                              void* d_out, int out_size, void* d_ws, size_t ws_size,
                              hipStream_t stream) {
    const float* x    = (const float*)d_in[0];
    const int*   ei   = (const int*)d_in[1];
    const int*   batch= (const int*)d_in[2];
    const float* W1   = (const float*)d_in[3];
    const float* b1   = (const float*)d_in[4];
    const float* W2   = (const float*)d_in[5];
    const float* b2   = (const float*)d_in[6];
    const float* ln1w = (const float*)d_in[7];
    const float* ln1b = (const float*)d_in[8];
    const float* ln2w = (const float*)d_in[9];
    const float* ln2b = (const float*)d_in[10];
    const float* linW = (const float*)d_in[11];
    const float* linb = (const float*)d_in[12];
    float* out = (float*)d_out;

    int nNodes  = in_sizes[0] / D;   // 50000
    int nEdges  = in_sizes[1] / 2;   // 800000
    int nGraphs = out_size / 10;     // 512

    const int* src = ei;
    const int* dst = ei + nEdges;

    char* ws = (char*)d_ws;
    size_t o = 0;
    auto alloc = [&](size_t bytes) -> char* {
        char* p = ws + o;
        o += (bytes + 511) & ~(size_t)511;
        return p;
    };
    unsigned short* xb = (unsigned short*)alloc((size_t)nNodes * D * 2);  // bf16 x / h2
    unsigned short* hW = (unsigned short*)alloc((size_t)nNodes * D * 2);  // bf16 gemm out
    unsigned short* h1 = (unsigned short*)alloc((size_t)nNodes * D * 2);  // bf16 LN out
    int* deg   = (int*)alloc((size_t)nNodes * 4);
    int* cur   = (int*)alloc((size_t)nNodes * 4);
    int* offs  = (int*)alloc((size_t)(nNodes + 1) * 4);
    int2* ew   = (int2*)alloc((size_t)nEdges * 8);
    float* dinv= (float*)alloc((size_t)nNodes * 4);
    int* bsum  = (int*)alloc(256 * 4);
    unsigned short* Wt1 = (unsigned short*)alloc((size_t)D * D * 2);
    unsigned short* Wt2 = (unsigned short*)alloc((size_t)D * D * 2);
    (void)ws_size;

    int gn = (nNodes + 255) / 256;   // 196 blocks
    int ge = (nEdges + 255) / 256;
    int n8 = nNodes * (D / 8);       // f2b work items
    int nf2b = (n8 + 255) / 256;     // 6250
    int ngemm = ((nNodes + 127) / 128) * 2;

    // CSR build (dst counting sort; hierarchical scan; per-edge weight fused)
    k_zero2<<<gn, 256, 0, stream>>>(deg, cur, nNodes);
    k_deg  <<<ge, 256, 0, stream>>>(dst, deg, nEdges);
    k_scan1<<<gn, 256, 0, stream>>>(deg, dinv, bsum, nNodes);
    k_scan2<<<1, 256, 0, stream>>>(bsum, offs, gn, nNodes);
    k_scan3<<<gn, 256, 0, stream>>>(deg, bsum, offs, nNodes);
    k_fill <<<ge, 256, 0, stream>>>(src, dst, offs, cur, dinv, ew, nEdges);

    // x -> bf16, W1/W2 -> transposed bf16 (single fused kernel)
    k_prep<<<nf2b + 512, 256, 0, stream>>>(x, xb, n8, W1, W2, Wt1, Wt2, nf2b);

    // layer 1
    k_gemm<<<ngemm, 256, 0, stream>>>(xb, Wt1, hW, nNodes);
    k_agg <<<(nNodes + 3) / 4, 256, 0, stream>>>(hW, offs, ew, dinv, b1, ln1w, ln1b, h1, nNodes);

    // layer 2 (reuse xb as h2)
    k_gemm<<<ngemm, 256, 0, stream>>>(h1, Wt2, hW, nNodes);
    k_agg <<<(nNodes + 3) / 4, 256, 0, stream>>>(hW, offs, ew, dinv, b2, ln2w, ln2b, xb, nNodes);

    // pool + classifier
    k_pool<<<nGraphs, 256, 0, stream>>>(xb, batch, linW, linb, out, nNodes);
}